// Round 4
// baseline (93.061 us; speedup 1.0000x reference)
//
#include <hip/hip_runtime.h>

#define D_FEAT 128
#define CAP 128
#define MAX_OVF 4096
#define NPART 8

// ---------------- XCD-partitioned bucket-CSR build ----------------
// Block b handles partition r = b & 7 (round-robin dispatch puts r on XCD r)
// and edge chunks {q, q+Q, q+2Q, ...} with q = b >> 3. Every csr/cnt line for
// a node in partition r is written ONLY by blocks with that r -> lines stay in
// one XCD's L2 instead of bouncing between 8.
__global__ void fill_part_kernel(const int* __restrict__ src,
                                 const int* __restrict__ dst,
                                 int* __restrict__ cnt,
                                 int* __restrict__ ovf_cnt,
                                 int* __restrict__ ovf,
                                 int* __restrict__ csr,
                                 int n_edges, int nodes_per_part,
                                 int q_count, int chunks) {
    int r = blockIdx.x & (NPART - 1);
    int q = blockIdx.x >> 3;
    int lo = r * nodes_per_part;
    int hi = lo + nodes_per_part;
    for (int c = q; c < chunks; c += q_count) {
        int e = c * blockDim.x + threadIdx.x;
        if (e < n_edges) {
            int d = dst[e];
            if (d >= lo && d < hi) {
                int sid = src[e];
                int pos = atomicAdd(&cnt[d], 1);
                if (pos < CAP) {
                    csr[(long long)d * CAP + pos] = sid;
                } else {
                    int o = atomicAdd(ovf_cnt, 1);
                    if (o < MAX_OVF) { ovf[2 * o] = sid; ovf[2 * o + 1] = d; }
                }
            }
        }
    }
}

// ---------------- gather: 2 nodes per wave, float4 per lane ----------------
// Half-wave (32 lanes) owns one node; lane owns 4 feature columns. One
// global_load_dwordx4 per lane serves a full 512B row for each half -> 1KB
// per wave per instruction. Edge ids broadcast per-half via __shfl(width=32).
__global__ void gather2_kernel(const float* __restrict__ feat,
                               const int* __restrict__ cnt,
                               const int* __restrict__ csr,
                               float* __restrict__ out,
                               int n_nodes) {
    int gtid = blockIdx.x * blockDim.x + threadIdx.x;
    int wid  = gtid >> 6;
    int lane = gtid & 63;
    int hl   = lane & 31;           // lane within half
    int node = wid * 2 + (lane >> 5);
    bool valid = node < n_nodes;
    int nc = valid ? node : (n_nodes - 1);
    int full = cnt[nc];
    int deg  = valid ? (full < CAP ? full : CAP) : 0;
    int degO = __shfl_xor(deg, 32);       // other half's degree
    int degW = deg > degO ? deg : degO;   // wave-uniform loop bound

    const float4* f4  = (const float4*)feat;          // 32 float4 per row
    const int*    base = csr + (long long)nc * CAP;

    float4 a0 = {0,0,0,0}, a1 = {0,0,0,0}, a2 = {0,0,0,0}, a3 = {0,0,0,0};
    for (int chunk = 0; chunk < degW; chunk += 32) {
        int idx = chunk + hl;
        int eid = 0;
        if (idx < deg) eid = base[idx];   // coalesced per-half id load
        int m  = deg - chunk;             // edges left for THIS half (uniform per half)
        int mW = degW - chunk; if (mW > 32) mW = 32;
        for (int j = 0; j < mW; j += 4) {
            int s0 = __shfl(eid, j,     32);
            int s1 = __shfl(eid, j + 1, 32);
            int s2 = __shfl(eid, j + 2, 32);
            int s3 = __shfl(eid, j + 3, 32);
            if (j < m) {
                float4 v = f4[(size_t)s0 * 32 + hl];
                a0.x += v.x; a0.y += v.y; a0.z += v.z; a0.w += v.w;
            }
            if (j + 1 < m) {
                float4 v = f4[(size_t)s1 * 32 + hl];
                a1.x += v.x; a1.y += v.y; a1.z += v.z; a1.w += v.w;
            }
            if (j + 2 < m) {
                float4 v = f4[(size_t)s2 * 32 + hl];
                a2.x += v.x; a2.y += v.y; a2.z += v.z; a2.w += v.w;
            }
            if (j + 3 < m) {
                float4 v = f4[(size_t)s3 * 32 + hl];
                a3.x += v.x; a3.y += v.y; a3.z += v.z; a3.w += v.w;
            }
        }
    }
    float4 rr;
    rr.x = (a0.x + a1.x) + (a2.x + a3.x);
    rr.y = (a0.y + a1.y) + (a2.y + a3.y);
    rr.z = (a0.z + a1.z) + (a2.z + a3.z);
    rr.w = (a0.w + a1.w) + (a2.w + a3.w);
    float sc = rsqrtf((float)(full > 1 ? full : 1));
    rr.x *= sc; rr.y *= sc; rr.z *= sc; rr.w *= sc;
    if (valid) ((float4*)out)[(size_t)node * 32 + hl] = rr;
}

// Handle bucket-overflow edges (expected: none). Adds normalized
// contributions on top of gather's output.
__global__ void patch_kernel(const float* __restrict__ feat,
                             const int* __restrict__ cnt,
                             const int* __restrict__ ovf_cnt,
                             const int* __restrict__ ovf,
                             float* __restrict__ out) {
    int novf = *ovf_cnt;
    if (novf > MAX_OVF) novf = MAX_OVF;
    long long total  = (long long)novf * D_FEAT;
    long long stride = (long long)gridDim.x * blockDim.x;
    for (long long i = (long long)blockIdx.x * blockDim.x + threadIdx.x;
         i < total; i += stride) {
        int o = (int)(i >> 7);
        int f = (int)(i & 127);
        int s = ovf[2 * o];
        int d = ovf[2 * o + 1];
        int dgi = cnt[d]; if (dgi < 1) dgi = 1;
        float v = feat[(long long)s * D_FEAT + f] * rsqrtf((float)dgi);
        atomicAdd(&out[(long long)d * D_FEAT + f], v);
    }
}

// ---------------- fallback path (fp32 atomics) ----------------

__global__ void zero_kernel(float* __restrict__ out, float* __restrict__ deg,
                            int n_out, int n_deg) {
    int i = blockIdx.x * blockDim.x + threadIdx.x;
    if (i < n_out) out[i] = 0.0f;
    if (i < n_deg) deg[i] = 0.0f;
}

__global__ void scatter_kernel(const float* __restrict__ feat,
                               const int* __restrict__ src,
                               const int* __restrict__ dst,
                               float* __restrict__ out,
                               float* __restrict__ deg,
                               int n_edges) {
    long long gid = (long long)blockIdx.x * blockDim.x + threadIdx.x;
    int e = (int)(gid >> 7);
    int f = (int)(gid & 127);
    if (e >= n_edges) return;
    int s = src[e];
    int d = dst[e];
    float v = feat[(long long)s * D_FEAT + f];
    atomicAdd(&out[(long long)d * D_FEAT + f], v);
    if (f == 0) atomicAdd(&deg[d], 1.0f);
}

__global__ void norm_kernel(float* __restrict__ out, const float* __restrict__ deg,
                            int n_out) {
    int gid = blockIdx.x * blockDim.x + threadIdx.x;
    if (gid >= n_out) return;
    int i = gid >> 7;
    float dg = fmaxf(deg[i], 1.0f);
    out[gid] = out[gid] * rsqrtf(dg);
}

extern "C" void kernel_launch(void* const* d_in, const int* in_sizes, int n_in,
                              void* d_out, int out_size, void* d_ws, size_t ws_size,
                              hipStream_t stream) {
    const float* feat = (const float*)d_in[0];
    const int*   src  = (const int*)d_in[1];
    const int*   dst  = (const int*)d_in[2];
    float* out = (float*)d_out;

    const int n_edges = in_sizes[1];
    const int n_out   = out_size;           // n_nodes * 128
    const int n_nodes = n_out / D_FEAT;

    // ws layout: cnt[n_nodes] | ovf_cnt[1] | pad[1] | ovf[2*MAX_OVF] | csr[n_nodes*CAP]
    size_t need = (size_t)(n_nodes + 2 + 2 * MAX_OVF + (size_t)n_nodes * CAP)
                  * sizeof(int);

    if (ws_size >= need) {
        int* cnt     = (int*)d_ws;
        int* ovf_cnt = cnt + n_nodes;
        int* ovf     = cnt + n_nodes + 2;
        int* csr     = ovf + 2 * MAX_OVF;

        // zero cnt + ovf_cnt (+pad)
        hipMemsetAsync(cnt, 0, (size_t)(n_nodes + 2) * sizeof(int), stream);

        {
            int threads = 256;
            int chunks  = (n_edges + threads - 1) / threads;
            int CPB     = 4;                           // chunks per block
            int q_count = (chunks + CPB - 1) / CPB;
            int blocks  = q_count * NPART;
            int npp     = (n_nodes + NPART - 1) / NPART;
            fill_part_kernel<<<blocks, threads, 0, stream>>>(
                src, dst, cnt, ovf_cnt, ovf, csr, n_edges, npp, q_count, chunks);
        }
        {
            int threads = 256;                 // 4 waves/block, 2 nodes/wave
            int waves   = (n_nodes + 1) / 2;
            int blocks  = (waves * 64 + threads - 1) / threads;
            gather2_kernel<<<blocks, threads, 0, stream>>>(feat, cnt, csr, out,
                                                           n_nodes);
        }
        patch_kernel<<<32, 256, 0, stream>>>(feat, cnt, ovf_cnt, ovf, out);
    } else {
        float* deg = (float*)d_ws;
        {
            int threads = 256;
            int blocks = (n_out + threads - 1) / threads;
            zero_kernel<<<blocks, threads, 0, stream>>>(out, deg, n_out, n_nodes);
        }
        {
            long long total = (long long)n_edges * D_FEAT;
            int threads = 256;
            int blocks = (int)((total + threads - 1) / threads);
            scatter_kernel<<<blocks, threads, 0, stream>>>(feat, src, dst, out, deg, n_edges);
        }
        {
            int threads = 256;
            int blocks = (n_out + threads - 1) / threads;
            norm_kernel<<<blocks, threads, 0, stream>>>(out, deg, n_out);
        }
    }
}